// Round 2
// baseline (2628.172 us; speedup 1.0000x reference)
//
#include <hip/hip_runtime.h>
#include <math.h>

typedef unsigned short u16;
typedef unsigned int u32;
typedef short bf16x8 __attribute__((ext_vector_type(8)));
typedef float f32x4 __attribute__((ext_vector_type(4)));

#define TT 5
#define HEADS 6
#define HD 32
#define DIM 192
#define NWIN 320              // tokens per window = T*8*8
#define LTOK (TT*64*64)       // 20480
#define BATCH 2
#define MROWS (BATCH*LTOK)    // 40960
#define QSCALE 0.17677669529663687f   // 1/sqrt(32)

__device__ __forceinline__ u16 f2bf(float f) {
    u32 u = __float_as_uint(f);
    u32 r = (u + 0x7FFFu + ((u >> 16) & 1u)) >> 16;
    return (u16)r;
}
__device__ __forceinline__ float bflo(u32 u) { return __uint_as_float(u << 16); }
__device__ __forceinline__ float bfhi(u32 u) { return __uint_as_float(u & 0xFFFF0000u); }

// ---------------- fp32 -> bf16 weight conversion --------------------------
__global__ __launch_bounds__(256) void cvt_kernel(
    const float* __restrict__ in, u16* __restrict__ out, int n)
{
    int i = blockIdx.x * 256 + threadIdx.x;
    if (i < n) out[i] = f2bf(in[i]);
}

// ---------------- LayerNorm: one wave per token, bf16 output --------------
__global__ __launch_bounds__(256) void ln_kernel(
    const float* __restrict__ x, const float* __restrict__ g,
    const float* __restrict__ b, u16* __restrict__ out)
{
    int tok  = blockIdx.x * 4 + (threadIdx.x >> 6);
    int lane = threadIdx.x & 63;
    const float* xr = x + (size_t)tok * DIM;
    float v0 = xr[lane], v1 = xr[lane + 64], v2 = xr[lane + 128];
    float s = v0 + v1 + v2;
    #pragma unroll
    for (int off = 32; off; off >>= 1) s += __shfl_xor(s, off, 64);
    float mu = s * (1.0f / 192.0f);
    float d0 = v0 - mu, d1 = v1 - mu, d2 = v2 - mu;
    float vs = d0 * d0 + d1 * d1 + d2 * d2;
    #pragma unroll
    for (int off = 32; off; off >>= 1) vs += __shfl_xor(vs, off, 64);
    float rstd = rsqrtf(vs * (1.0f / 192.0f) + 1e-5f);
    u16* orow = out + (size_t)tok * DIM;
    orow[lane]       = f2bf(d0 * rstd * g[lane]       + b[lane]);
    orow[lane + 64]  = f2bf(d1 * rstd * g[lane + 64]  + b[lane + 64]);
    orow[lane + 128] = f2bf(d2 * rstd * g[lane + 128] + b[lane + 128]);
}

// ---------------- bf16 MFMA GEMM: C = A(MxK) @ W(NxK)^T + bias ------------
// 128x64 tile, BK=64, 256 threads (4 waves, each 32 rows x 64 cols).
// global_load_lds width 16; LDS 16B slots XOR-swizzled by row to avoid the
// 128B-row-stride bank clash on ds_read_b128.
// EPI 0: bf16 store  1: GELU->bf16  2: win-rev+roll+shortcut fp32  3: fp32 +=
template<int EPI>
__global__ __launch_bounds__(256) void mfma_gemm(
    const u16* __restrict__ A, const u16* __restrict__ W,
    const float* __restrict__ bias, void* __restrict__ outp,
    const float* __restrict__ xin, int N, int K)
{
    __shared__ u16 As[128 * 64];   // 16 KB
    __shared__ u16 Bs[64 * 64];    //  8 KB
    const int tid  = threadIdx.x;
    const int lane = tid & 63, wv = tid >> 6;
    const int ln16 = lane & 15, quad = lane >> 4;
    const int bn = blockIdx.x, bm = blockIdx.y;

    const int srow = lane >> 3;             // 0..7 row within 8-row group
    const int sxor = (lane & 7) ^ srow;     // swizzled 16B chunk 0..7
    const int acol = sxor * 8;              // bf16 elems

    f32x4 acc[2][4] = {};

    for (int k0 = 0; k0 < K; k0 += 64) {
        __syncthreads();
        #pragma unroll
        for (int a = 0; a < 4; ++a) {
            const u16* g = A + (size_t)(bm * 128 + a * 32 + wv * 8 + srow) * K + k0 + acol;
            __builtin_amdgcn_global_load_lds(
                (const __attribute__((address_space(1))) u32*)g,
                (__attribute__((address_space(3))) u32*)((char*)As + a * 4096 + wv * 1024),
                16, 0, 0);
        }
        #pragma unroll
        for (int bb = 0; bb < 2; ++bb) {
            const u16* g = W + (size_t)(bn * 64 + bb * 32 + wv * 8 + srow) * K + k0 + acol;
            __builtin_amdgcn_global_load_lds(
                (const __attribute__((address_space(1))) u32*)g,
                (__attribute__((address_space(3))) u32*)((char*)Bs + bb * 4096 + wv * 1024),
                16, 0, 0);
        }
        __syncthreads();
        #pragma unroll
        for (int s = 0; s < 2; ++s) {
            bf16x8 af[2], bf[4];
            #pragma unroll
            for (int i = 0; i < 2; ++i) {
                int r = wv * 32 + i * 16 + ln16;
                int slot = (s * 4 + quad) ^ (r & 7);
                af[i] = *(const bf16x8*)((const char*)As + r * 128 + slot * 16);
            }
            #pragma unroll
            for (int j = 0; j < 4; ++j) {
                int r = j * 16 + ln16;
                int slot = (s * 4 + quad) ^ (r & 7);
                bf[j] = *(const bf16x8*)((const char*)Bs + r * 128 + slot * 16);
            }
            #pragma unroll
            for (int i = 0; i < 2; ++i)
                #pragma unroll
                for (int j = 0; j < 4; ++j)
                    acc[i][j] = __builtin_amdgcn_mfma_f32_16x16x32_bf16(
                        af[i], bf[j], acc[i][j], 0, 0, 0);
        }
    }

    #pragma unroll
    for (int i = 0; i < 2; ++i) {
        int gr0 = bm * 128 + wv * 32 + i * 16 + quad * 4;
        #pragma unroll
        for (int j = 0; j < 4; ++j) {
            int gc = bn * 64 + j * 16 + ln16;
            float bv = bias[gc];
            #pragma unroll
            for (int rr = 0; rr < 4; ++rr) {
                int gr = gr0 + rr;
                float val = acc[i][j][rr] + bv;
                if (EPI == 0) {
                    ((u16*)outp)[(size_t)gr * N + gc] = f2bf(val);
                } else if (EPI == 1) {
                    float gl = val * 0.5f * (1.0f + erff(val * 0.70710678118654752f));
                    ((u16*)outp)[(size_t)gr * N + gc] = f2bf(gl);
                } else if (EPI == 2) {
                    int b_ = gr / NWIN, n = gr - b_ * NWIN;
                    int b = b_ >> 6, hb = (b_ >> 3) & 7, wb = b_ & 7;
                    int t = n >> 6, hi = (n >> 3) & 7, wj = n & 7;
                    int hs = (hb * 8 + hi + 4) & 63;
                    int wsrc = (wb * 8 + wj + 4) & 63;
                    size_t dst = ((size_t)b * LTOK + t * 4096 + hs * 64 + wsrc) * DIM + gc;
                    ((float*)outp)[dst] = xin[dst] + val;
                } else {
                    ((float*)outp)[(size_t)gr * N + gc] += val;
                }
            }
        }
    }
}

// ---------------- Windowed attention: block = (window, head), 320 threads --
// bf16 qkv input; K/V staged to LDS as fp32 (padded rows); chunked online
// softmax: 16 scores buffered, one branchless rescale per chunk, 4-way ILP dot.
__global__ __launch_bounds__(320, 4) void attn_kernel(
    const u16* __restrict__ qkv, const float* __restrict__ table,
    u16* __restrict__ attout)
{
    const int head = blockIdx.x % HEADS;
    const int b_   = blockIdx.x / HEADS;
    const int b = b_ >> 6, hb = (b_ >> 3) & 7, wb = b_ & 7;
    const int n = threadIdx.x;

    __shared__ float kbuf[160][36];   // +4 pad: spreads row-stride across banks
    __shared__ float vbuf[160][36];
    __shared__ float tbl[192];
    __shared__ int offm[NWIN];
    __shared__ unsigned char regm[NWIN];

    const int t1 = n >> 6, r1 = (n >> 3) & 7, c1 = n & 7;
    const int h1 = hb * 8 + r1, w1 = wb * 8 + c1;
    const int l1 = t1 * 4096 + ((h1 + 4) & 63) * 64 + ((w1 + 4) & 63);
    const u16* myrow = qkv + ((size_t)b * LTOK + l1) * (3 * DIM) + head * HD;

    float q[HD];
    #pragma unroll
    for (int i = 0; i < 4; ++i) {
        uint4 u = ((const uint4*)myrow)[i];
        q[8*i+0] = bflo(u.x) * QSCALE; q[8*i+1] = bfhi(u.x) * QSCALE;
        q[8*i+2] = bflo(u.y) * QSCALE; q[8*i+3] = bfhi(u.y) * QSCALE;
        q[8*i+4] = bflo(u.z) * QSCALE; q[8*i+5] = bfhi(u.z) * QSCALE;
        q[8*i+6] = bflo(u.w) * QSCALE; q[8*i+7] = bfhi(u.w) * QSCALE;
    }
    offm[n] = (7 - t1) * 15 + 7 - r1 - c1;
    int rh = h1 < 56 ? 0 : (h1 < 60 ? 1 : 2);
    int rw = w1 < 56 ? 0 : (w1 < 60 ? 1 : 2);
    const int myreg = rh * 3 + rw;
    regm[n] = (unsigned char)myreg;
    if (n < 187) tbl[n] = table[n * HEADS + head];
    const int base_n = t1 * 15 + r1 + c1;

    float mx = -1e30f, ssum = 0.0f;
    float acc[HD] = {};

    for (int chunk = 0; chunk < 2; ++chunk) {
        __syncthreads();   // protects LDS reuse + first-pass metadata
        {
            int half = (n >= 160) ? 1 : 0;
            int mloc = n - half * 160;
            int m = chunk * 160 + mloc;
            int tm = m >> 6, rm = (m >> 3) & 7, cm = m & 7;
            int lm = tm * 4096 + ((hb * 8 + rm + 4) & 63) * 64 + ((wb * 8 + cm + 4) & 63);
            const u16* src = qkv + ((size_t)b * LTOK + lm) * (3 * DIM)
                             + (half ? 2 * DIM : DIM) + head * HD;
            float* dstp = half ? vbuf[mloc] : kbuf[mloc];
            #pragma unroll
            for (int i = 0; i < 4; ++i) {
                uint4 u = ((const uint4*)src)[i];
                float4 lo4 = { bflo(u.x), bfhi(u.x), bflo(u.y), bfhi(u.y) };
                float4 hi4 = { bflo(u.z), bfhi(u.z), bflo(u.w), bfhi(u.w) };
                *(float4*)(dstp + 8 * i)     = lo4;
                *(float4*)(dstp + 8 * i + 4) = hi4;
            }
        }
        __syncthreads();
        #pragma unroll 1
        for (int kk0 = 0; kk0 < 160; kk0 += 16) {
            float sc[16];
            #pragma unroll
            for (int t = 0; t < 16; ++t) {
                const float* kr = kbuf[kk0 + t];
                float s0 = 0, s1 = 0, s2 = 0, s3 = 0;
                #pragma unroll
                for (int d = 0; d < HD; d += 4) {
                    s0 = fmaf(q[d+0], kr[d+0], s0);
                    s1 = fmaf(q[d+1], kr[d+1], s1);
                    s2 = fmaf(q[d+2], kr[d+2], s2);
                    s3 = fmaf(q[d+3], kr[d+3], s3);
                }
                int m = chunk * 160 + kk0 + t;
                float s = (s0 + s1) + (s2 + s3) + tbl[base_n + offm[m]];
                s += (regm[m] != myreg) ? -100.0f : 0.0f;
                sc[t] = s;
            }
            float cm = sc[0];
            #pragma unroll
            for (int t = 1; t < 16; ++t) cm = fmaxf(cm, sc[t]);
            float nm = fmaxf(mx, cm);
            float rs = __expf(mx - nm);
            mx = nm;
            ssum *= rs;
            #pragma unroll
            for (int d = 0; d < HD; ++d) acc[d] *= rs;
            #pragma unroll
            for (int t = 0; t < 16; ++t) {
                float e = __expf(sc[t] - mx);
                ssum += e;
                const float* vr = vbuf[kk0 + t];
                #pragma unroll
                for (int d = 0; d < HD; ++d) acc[d] = fmaf(e, vr[d], acc[d]);
            }
        }
    }
    float inv = 1.0f / ssum;
    u16* orow = attout + ((size_t)b_ * NWIN + n) * DIM + head * HD;
    #pragma unroll
    for (int d = 0; d < HD; ++d) orow[d] = f2bf(acc[d] * inv);
}

// ---------------------------------------------------------------------------
extern "C" void kernel_launch(void* const* d_in, const int* in_sizes, int n_in,
                              void* d_out, int out_size, void* d_ws, size_t ws_size,
                              hipStream_t stream)
{
    (void)in_sizes; (void)n_in; (void)out_size; (void)ws_size;
    const float* x      = (const float*)d_in[0];
    const float* ln1_g  = (const float*)d_in[1];
    const float* ln1_b  = (const float*)d_in[2];
    const float* qkv_w  = (const float*)d_in[3];
    const float* qkv_b  = (const float*)d_in[4];
    const float* table  = (const float*)d_in[5];
    const float* proj_w = (const float*)d_in[6];
    const float* proj_b = (const float*)d_in[7];
    const float* ln2_g  = (const float*)d_in[8];
    const float* ln2_b  = (const float*)d_in[9];
    const float* fc1_w  = (const float*)d_in[10];
    const float* fc1_b  = (const float*)d_in[11];
    const float* fc2_w  = (const float*)d_in[12];
    const float* fc2_b  = (const float*)d_in[13];
    float* out = (float*)d_out;

    // ws layout (bf16 elems): h [M*192] | qkv [M*576] | att [M*192] | weights
    // fc1 [M*768] overlays qkv+att exactly (both dead by then).
    u16* wsu     = (u16*)d_ws;
    u16* h_buf   = wsu;
    u16* qkv_buf = wsu + (size_t)MROWS * DIM;
    u16* att_buf = wsu + (size_t)MROWS * (4 * DIM);
    u16* fc1_buf = wsu + (size_t)MROWS * DIM;
    u16* wq = wsu + (size_t)MROWS * (5 * DIM);
    u16* wp = wq + 3 * DIM * DIM;
    u16* w1 = wp + DIM * DIM;
    u16* w2 = w1 + 4 * DIM * DIM;

    // weight conversion (0.44M elems total)
    cvt_kernel<<<3 * DIM * DIM / 256, 256, 0, stream>>>(qkv_w, wq, 3 * DIM * DIM);
    cvt_kernel<<<DIM * DIM / 256, 256, 0, stream>>>(proj_w, wp, DIM * DIM);
    cvt_kernel<<<4 * DIM * DIM / 256, 256, 0, stream>>>(fc1_w, w1, 4 * DIM * DIM);
    cvt_kernel<<<4 * DIM * DIM / 256, 256, 0, stream>>>(fc2_w, w2, 4 * DIM * DIM);

    // LN1 -> h (bf16)
    ln_kernel<<<MROWS / 4, 256, 0, stream>>>(x, ln1_g, ln1_b, h_buf);
    // QKV: (M,192)@(576,192)^T -> bf16
    mfma_gemm<0><<<dim3(3 * DIM / 64, MROWS / 128), 256, 0, stream>>>(
        h_buf, wq, qkv_b, qkv_buf, nullptr, 3 * DIM, DIM);
    // Attention per (window, head) -> bf16
    attn_kernel<<<128 * HEADS, 320, 0, stream>>>(qkv_buf, table, att_buf);
    // Proj + window-reverse + roll + shortcut -> out (fp32)
    mfma_gemm<2><<<dim3(DIM / 64, MROWS / 128), 256, 0, stream>>>(
        att_buf, wp, proj_b, out, x, DIM, DIM);
    // LN2 -> h (bf16)
    ln_kernel<<<MROWS / 4, 256, 0, stream>>>(out, ln2_g, ln2_b, h_buf);
    // FC1 + GELU -> bf16
    mfma_gemm<1><<<dim3(4 * DIM / 64, MROWS / 128), 256, 0, stream>>>(
        h_buf, w1, fc1_b, fc1_buf, nullptr, 4 * DIM, DIM);
    // FC2, accumulate into residual (fp32)
    mfma_gemm<3><<<dim3(DIM / 64, MROWS / 128), 256, 0, stream>>>(
        fc1_buf, w2, fc2_b, out, nullptr, DIM, 4 * DIM);
}

// Round 4
// 295.511 us; speedup vs baseline: 8.8936x; 8.8936x over previous
//
#include <hip/hip_runtime.h>
#include <math.h>

typedef unsigned short u16;
typedef unsigned int u32;
typedef short bf16x8 __attribute__((ext_vector_type(8)));
typedef float f32x4 __attribute__((ext_vector_type(4)));
typedef _Float16 f16x4 __attribute__((ext_vector_type(4)));

#define TT 5
#define HEADS 6
#define HD 32
#define DIM 192
#define NWIN 320              // tokens per window = T*8*8
#define LTOK (TT*64*64)       // 20480
#define BATCH 2
#define MROWS (BATCH*LTOK)    // 40960
#define QSCALE 0.17677669529663687f   // 1/sqrt(32)

__device__ __forceinline__ u16 f2bf(float f) {
    u32 u = __float_as_uint(f);
    u32 r = (u + 0x7FFFu + ((u >> 16) & 1u)) >> 16;
    return (u16)r;
}
__device__ __forceinline__ float bflo(u32 u) { return __uint_as_float(u << 16); }
__device__ __forceinline__ float bfhi(u32 u) { return __uint_as_float(u & 0xFFFF0000u); }
__device__ __forceinline__ u32 pkh(float a, float b) {
    auto h = __builtin_amdgcn_cvt_pkrtz(a, b);
    return __builtin_bit_cast(u32, h);
}

// ---------------- fp32 -> bf16 weight conversion --------------------------
__global__ __launch_bounds__(256) void cvt_kernel(
    const float* __restrict__ in, u16* __restrict__ out, int n)
{
    int i = blockIdx.x * 256 + threadIdx.x;
    if (i < n) out[i] = f2bf(in[i]);
}

// ---------------- LayerNorm: one wave per token, bf16 output --------------
__global__ __launch_bounds__(256) void ln_kernel(
    const float* __restrict__ x, const float* __restrict__ g,
    const float* __restrict__ b, u16* __restrict__ out)
{
    int tok  = blockIdx.x * 4 + (threadIdx.x >> 6);
    int lane = threadIdx.x & 63;
    const float* xr = x + (size_t)tok * DIM;
    float v0 = xr[lane], v1 = xr[lane + 64], v2 = xr[lane + 128];
    float s = v0 + v1 + v2;
    #pragma unroll
    for (int off = 32; off; off >>= 1) s += __shfl_xor(s, off, 64);
    float mu = s * (1.0f / 192.0f);
    float d0 = v0 - mu, d1 = v1 - mu, d2 = v2 - mu;
    float vs = d0 * d0 + d1 * d1 + d2 * d2;
    #pragma unroll
    for (int off = 32; off; off >>= 1) vs += __shfl_xor(vs, off, 64);
    float rstd = rsqrtf(vs * (1.0f / 192.0f) + 1e-5f);
    u16* orow = out + (size_t)tok * DIM;
    orow[lane]       = f2bf(d0 * rstd * g[lane]       + b[lane]);
    orow[lane + 64]  = f2bf(d1 * rstd * g[lane + 64]  + b[lane + 64]);
    orow[lane + 128] = f2bf(d2 * rstd * g[lane + 128] + b[lane + 128]);
}

// ---------------- bf16 MFMA GEMM: C = A(MxK) @ W(NxK)^T + bias ------------
template<int EPI>
__global__ __launch_bounds__(256) void mfma_gemm(
    const u16* __restrict__ A, const u16* __restrict__ W,
    const float* __restrict__ bias, void* __restrict__ outp,
    const float* __restrict__ xin, int N, int K)
{
    __shared__ u16 As[128 * 64];
    __shared__ u16 Bs[64 * 64];
    const int tid  = threadIdx.x;
    const int lane = tid & 63, wv = tid >> 6;
    const int ln16 = lane & 15, quad = lane >> 4;
    const int bn = blockIdx.x, bm = blockIdx.y;

    const int srow = lane >> 3;
    const int sxor = (lane & 7) ^ srow;
    const int acol = sxor * 8;

    f32x4 acc[2][4] = {};

    for (int k0 = 0; k0 < K; k0 += 64) {
        __syncthreads();
        #pragma unroll
        for (int a = 0; a < 4; ++a) {
            const u16* g = A + (size_t)(bm * 128 + a * 32 + wv * 8 + srow) * K + k0 + acol;
            __builtin_amdgcn_global_load_lds(
                (const __attribute__((address_space(1))) u32*)g,
                (__attribute__((address_space(3))) u32*)((char*)As + a * 4096 + wv * 1024),
                16, 0, 0);
        }
        #pragma unroll
        for (int bb = 0; bb < 2; ++bb) {
            const u16* g = W + (size_t)(bn * 64 + bb * 32 + wv * 8 + srow) * K + k0 + acol;
            __builtin_amdgcn_global_load_lds(
                (const __attribute__((address_space(1))) u32*)g,
                (__attribute__((address_space(3))) u32*)((char*)Bs + bb * 4096 + wv * 1024),
                16, 0, 0);
        }
        __syncthreads();
        #pragma unroll
        for (int s = 0; s < 2; ++s) {
            bf16x8 af[2], bf[4];
            #pragma unroll
            for (int i = 0; i < 2; ++i) {
                int r = wv * 32 + i * 16 + ln16;
                int slot = (s * 4 + quad) ^ (r & 7);
                af[i] = *(const bf16x8*)((const char*)As + r * 128 + slot * 16);
            }
            #pragma unroll
            for (int j = 0; j < 4; ++j) {
                int r = j * 16 + ln16;
                int slot = (s * 4 + quad) ^ (r & 7);
                bf[j] = *(const bf16x8*)((const char*)Bs + r * 128 + slot * 16);
            }
            #pragma unroll
            for (int i = 0; i < 2; ++i)
                #pragma unroll
                for (int j = 0; j < 4; ++j)
                    acc[i][j] = __builtin_amdgcn_mfma_f32_16x16x32_bf16(
                        af[i], bf[j], acc[i][j], 0, 0, 0);
        }
    }

    #pragma unroll
    for (int i = 0; i < 2; ++i) {
        int gr0 = bm * 128 + wv * 32 + i * 16 + quad * 4;
        #pragma unroll
        for (int j = 0; j < 4; ++j) {
            int gc = bn * 64 + j * 16 + ln16;
            float bv = bias[gc];
            #pragma unroll
            for (int rr = 0; rr < 4; ++rr) {
                int gr = gr0 + rr;
                float val = acc[i][j][rr] + bv;
                if (EPI == 0) {
                    ((u16*)outp)[(size_t)gr * N + gc] = f2bf(val);
                } else if (EPI == 1) {
                    float gl = val * 0.5f * (1.0f + erff(val * 0.70710678118654752f));
                    ((u16*)outp)[(size_t)gr * N + gc] = f2bf(gl);
                } else if (EPI == 2) {
                    int b_ = gr / NWIN, n = gr - b_ * NWIN;
                    int b = b_ >> 6, hb = (b_ >> 3) & 7, wb = b_ & 7;
                    int t = n >> 6, hi = (n >> 3) & 7, wj = n & 7;
                    int hs = (hb * 8 + hi + 4) & 63;
                    int wsrc = (wb * 8 + wj + 4) & 63;
                    size_t dst = ((size_t)b * LTOK + t * 4096 + hs * 64 + wsrc) * DIM + gc;
                    ((float*)outp)[dst] = xin[dst] + val;
                } else {
                    ((float*)outp)[(size_t)gr * N + gc] += val;
                }
            }
        }
    }
}

// ---------------- MFMA flash attention: block = (window, head) ------------
// 5 waves x 64 q-rows each. S^T = K·Q^T via mfma_f32_16x16x32_bf16
// (C-layout: row=key, col=qrow). P^T feeds mfma_f32_16x16x16f16 B-operand
// directly (k=quad*4+j == C row=quad*4+r). O^T = V^T·P^T accumulated in regs.
__global__ __launch_bounds__(320) void attn_kernel(
    const u16* __restrict__ qkv, const float* __restrict__ table,
    u16* __restrict__ attout)
{
    const int head = blockIdx.x % HEADS;
    const int b_   = blockIdx.x / HEADS;
    const int b = b_ >> 6, hb = (b_ >> 3) & 7, wb = b_ & 7;
    const int tid = threadIdx.x;
    const int lane = tid & 63, wv = tid >> 6;
    const int ln16 = lane & 15, quad = lane >> 4;

    __shared__ u16 Ks[320 * 40];     // bf16, row pad 40 (16B-aligned rows)
    __shared__ u16 Vt[32 * 328];     // f16 transposed, row pad 328
    __shared__ u16 meta[320];        // off | (region<<8) per key token
    __shared__ float tbl[188];

    // ---- staging: thread tid = window token n -----------------------------
    {
        int n = tid;
        int t1 = n >> 6, r1 = (n >> 3) & 7, c1 = n & 7;
        int h1 = hb * 8 + r1, w1 = wb * 8 + c1;
        int l1 = t1 * 4096 + ((h1 + 4) & 63) * 64 + ((w1 + 4) & 63);
        const u16* src = qkv + ((size_t)b * LTOK + l1) * (3 * DIM) + head * HD;
        const uint4* k4 = (const uint4*)(src + DIM);
        #pragma unroll
        for (int i = 0; i < 4; ++i)
            *(uint4*)(Ks + n * 40 + i * 8) = k4[i];
        const uint4* v4 = (const uint4*)(src + 2 * DIM);
        #pragma unroll
        for (int i = 0; i < 4; ++i) {
            uint4 u = v4[i];
            u32 ws[4] = {u.x, u.y, u.z, u.w};
            #pragma unroll
            for (int j = 0; j < 4; ++j) {
                u32 hb2 = pkh(bflo(ws[j]), bfhi(ws[j]));
                int d = i * 8 + j * 2;
                Vt[d * 328 + n]       = (u16)(hb2 & 0xFFFF);
                Vt[(d + 1) * 328 + n] = (u16)(hb2 >> 16);
            }
        }
        int off = (7 - t1) * 15 + 7 - r1 - c1;
        int rh = h1 < 56 ? 0 : (h1 < 60 ? 1 : 2);
        int rw = w1 < 56 ? 0 : (w1 < 60 ? 1 : 2);
        meta[n] = (u16)(off | ((rh * 3 + rw) << 8));
        if (n < 187) tbl[n] = table[n * HEADS + head];
    }

    // ---- per-wave Q setup: 4 q-tiles of 16 rows ---------------------------
    bf16x8 qf[4];
    int basen[4], myreg[4];
    #pragma unroll
    for (int qt = 0; qt < 4; ++qt) {
        int nq = wv * 64 + qt * 16 + ln16;
        int t1 = nq >> 6, r1 = (nq >> 3) & 7, c1 = nq & 7;
        int h1 = hb * 8 + r1, w1 = wb * 8 + c1;
        int l1 = t1 * 4096 + ((h1 + 4) & 63) * 64 + ((w1 + 4) & 63);
        qf[qt] = *(const bf16x8*)(qkv + ((size_t)b * LTOK + l1) * (3 * DIM)
                                  + head * HD + quad * 8);
        basen[qt] = t1 * 15 + r1 + c1;
        int rh = h1 < 56 ? 0 : (h1 < 60 ? 1 : 2);
        int rw = w1 < 56 ? 0 : (w1 < 60 ? 1 : 2);
        myreg[qt] = rh * 3 + rw;
    }

    __syncthreads();

    f32x4 o[4][2] = {};          // [qtile][d-half]: O^T rows=d(quad*4+r), col=qrow(ln16)
    float m_[4] = {-1e30f, -1e30f, -1e30f, -1e30f};
    float l_[4] = {};
    const f32x4 zero = {};

    #pragma unroll 1
    for (int c = 0; c < 10; ++c) {
        int kb = c * 32;
        bf16x8 af0 = *(const bf16x8*)(Ks + (kb + ln16) * 40 + quad * 8);
        bf16x8 af1 = *(const bf16x8*)(Ks + (kb + 16 + ln16) * 40 + quad * 8);
        f16x4 va[2][2];
        #pragma unroll
        for (int dt = 0; dt < 2; ++dt)
            #pragma unroll
            for (int kt = 0; kt < 2; ++kt)
                va[dt][kt] = *(const f16x4*)(Vt + (dt * 16 + ln16) * 328
                                             + kb + kt * 16 + quad * 4);
        ushort4 m4a = *(const ushort4*)(meta + kb + quad * 4);
        ushort4 m4b = *(const ushort4*)(meta + kb + 16 + quad * 4);
        u16 mta[4] = {m4a.x, m4a.y, m4a.z, m4a.w};
        u16 mtb[4] = {m4b.x, m4b.y, m4b.z, m4b.w};

        #pragma unroll
        for (int qt = 0; qt < 4; ++qt) {
            f32x4 s0 = __builtin_amdgcn_mfma_f32_16x16x32_bf16(af0, qf[qt], zero, 0, 0, 0);
            f32x4 s1 = __builtin_amdgcn_mfma_f32_16x16x32_bf16(af1, qf[qt], zero, 0, 0, 0);
            float p[8];
            #pragma unroll
            for (int r = 0; r < 4; ++r) {
                int ma = mta[r], mb = mtb[r];
                float va0 = fmaf(s0[r], QSCALE, tbl[basen[qt] + (ma & 0xFF)]);
                float vb0 = fmaf(s1[r], QSCALE, tbl[basen[qt] + (mb & 0xFF)]);
                p[r]     = va0 + (((ma >> 8) == myreg[qt]) ? 0.0f : -100.0f);
                p[4 + r] = vb0 + (((mb >> 8) == myreg[qt]) ? 0.0f : -100.0f);
            }
            float cm = p[0];
            #pragma unroll
            for (int j = 1; j < 8; ++j) cm = fmaxf(cm, p[j]);
            cm = fmaxf(cm, __shfl_xor(cm, 16, 64));
            cm = fmaxf(cm, __shfl_xor(cm, 32, 64));
            float mn = fmaxf(m_[qt], cm);
            float rs = __expf(m_[qt] - mn);
            m_[qt] = mn;
            float ls = 0.0f;
            #pragma unroll
            for (int j = 0; j < 8; ++j) { p[j] = __expf(p[j] - mn); ls += p[j]; }
            l_[qt] = l_[qt] * rs + ls;
            #pragma unroll
            for (int dt = 0; dt < 2; ++dt) {
                o[qt][dt][0] *= rs; o[qt][dt][1] *= rs;
                o[qt][dt][2] *= rs; o[qt][dt][3] *= rs;
            }
            uint2 pk0 = { pkh(p[0], p[1]), pkh(p[2], p[3]) };
            uint2 pk1 = { pkh(p[4], p[5]), pkh(p[6], p[7]) };
            f16x4 pf0 = __builtin_bit_cast(f16x4, pk0);
            f16x4 pf1 = __builtin_bit_cast(f16x4, pk1);
            #pragma unroll
            for (int dt = 0; dt < 2; ++dt) {
                o[qt][dt] = __builtin_amdgcn_mfma_f32_16x16x16f16(va[dt][0], pf0, o[qt][dt], 0, 0, 0);
                o[qt][dt] = __builtin_amdgcn_mfma_f32_16x16x16f16(va[dt][1], pf1, o[qt][dt], 0, 0, 0);
            }
        }
    }

    // ---- epilogue: normalize, pack bf16, store O (token-major) ------------
    #pragma unroll
    for (int qt = 0; qt < 4; ++qt) {
        float lt = l_[qt];
        lt += __shfl_xor(lt, 16, 64);
        lt += __shfl_xor(lt, 32, 64);
        float inv = 1.0f / lt;
        int nq = wv * 64 + qt * 16 + ln16;
        u16* dst = attout + ((size_t)(b_ * NWIN + nq)) * DIM + head * HD + quad * 4;
        #pragma unroll
        for (int dt = 0; dt < 2; ++dt) {
            u32 w0 = (u32)f2bf(o[qt][dt][0] * inv) | ((u32)f2bf(o[qt][dt][1] * inv) << 16);
            u32 w1 = (u32)f2bf(o[qt][dt][2] * inv) | ((u32)f2bf(o[qt][dt][3] * inv) << 16);
            uint2 st = {w0, w1};
            *(uint2*)(dst + dt * 16) = st;
        }
    }
}

// ---------------------------------------------------------------------------
extern "C" void kernel_launch(void* const* d_in, const int* in_sizes, int n_in,
                              void* d_out, int out_size, void* d_ws, size_t ws_size,
                              hipStream_t stream)
{
    (void)in_sizes; (void)n_in; (void)out_size; (void)ws_size;
    const float* x      = (const float*)d_in[0];
    const float* ln1_g  = (const float*)d_in[1];
    const float* ln1_b  = (const float*)d_in[2];
    const float* qkv_w  = (const float*)d_in[3];
    const float* qkv_b  = (const float*)d_in[4];
    const float* table  = (const float*)d_in[5];
    const float* proj_w = (const float*)d_in[6];
    const float* proj_b = (const float*)d_in[7];
    const float* ln2_g  = (const float*)d_in[8];
    const float* ln2_b  = (const float*)d_in[9];
    const float* fc1_w  = (const float*)d_in[10];
    const float* fc1_b  = (const float*)d_in[11];
    const float* fc2_w  = (const float*)d_in[12];
    const float* fc2_b  = (const float*)d_in[13];
    float* out = (float*)d_out;

    u16* wsu     = (u16*)d_ws;
    u16* h_buf   = wsu;
    u16* qkv_buf = wsu + (size_t)MROWS * DIM;
    u16* att_buf = wsu + (size_t)MROWS * (4 * DIM);
    u16* fc1_buf = wsu + (size_t)MROWS * DIM;
    u16* wq = wsu + (size_t)MROWS * (5 * DIM);
    u16* wp = wq + 3 * DIM * DIM;
    u16* w1 = wp + DIM * DIM;
    u16* w2 = w1 + 4 * DIM * DIM;

    cvt_kernel<<<3 * DIM * DIM / 256, 256, 0, stream>>>(qkv_w, wq, 3 * DIM * DIM);
    cvt_kernel<<<DIM * DIM / 256, 256, 0, stream>>>(proj_w, wp, DIM * DIM);
    cvt_kernel<<<4 * DIM * DIM / 256, 256, 0, stream>>>(fc1_w, w1, 4 * DIM * DIM);
    cvt_kernel<<<4 * DIM * DIM / 256, 256, 0, stream>>>(fc2_w, w2, 4 * DIM * DIM);

    ln_kernel<<<MROWS / 4, 256, 0, stream>>>(x, ln1_g, ln1_b, h_buf);
    mfma_gemm<0><<<dim3(3 * DIM / 64, MROWS / 128), 256, 0, stream>>>(
        h_buf, wq, qkv_b, qkv_buf, nullptr, 3 * DIM, DIM);
    attn_kernel<<<128 * HEADS, 320, 0, stream>>>(qkv_buf, table, att_buf);
    mfma_gemm<2><<<dim3(DIM / 64, MROWS / 128), 256, 0, stream>>>(
        att_buf, wp, proj_b, out, x, DIM, DIM);
    ln_kernel<<<MROWS / 4, 256, 0, stream>>>(out, ln2_g, ln2_b, h_buf);
    mfma_gemm<1><<<dim3(4 * DIM / 64, MROWS / 128), 256, 0, stream>>>(
        h_buf, w1, fc1_b, fc1_buf, nullptr, 4 * DIM, DIM);
    mfma_gemm<3><<<dim3(DIM / 64, MROWS / 128), 256, 0, stream>>>(
        fc1_buf, w2, fc2_b, out, nullptr, DIM, 4 * DIM);
}